// Round 10
// baseline (120.748 us; speedup 1.0000x reference)
//
#include <hip/hip_runtime.h>
#include <math.h>

#define NB   1024
#define CH   60
#define SW   288
#define F1C  8
#define FD   16   // F1*D
#define F2C  16
#define KLEN 64
#define NCLS 4
#define NV   9
#define FEAT 144
#define NTHR 320
#define NREP 4    // class-sum replicas (atomic contention / 4)

#define XR_STRIDE 356   // mult of 4 (b128-aligned rows)
#define PH_STRIDE 76
#define W1_STRIDE 68

__device__ __forceinline__ float elu1(float v) {
    return v > 0.f ? v : __expf(v) - 1.f;   // native v_exp_f32
}

// ===== fused per-sample forward: chreduce -> conv -> pointwise -> softmax ===
// 1024 blocks x 320 threads (grid-shape fixes 20 waves/CU; optimize stalls).
// Phase 1 is explicitly software-pipelined: 4x15-channel batches, loads of
// batch k+1 pinned ABOVE FMAs of batch k via sched_barrier(0). Peak live regs
// 15+15+16=46 -> fits the <=64-VGPR/8-wave bucket (launch_bounds cap).
__global__ __launch_bounds__(NTHR, 8) void eegnet_fwd(
    const float* __restrict__ x, const int* __restrict__ y,
    const float* __restrict__ conv1_w,
    const float* __restrict__ bn1_g, const float* __restrict__ bn1_b,
    const float* __restrict__ bn1_m, const float* __restrict__ bn1_v,
    const float* __restrict__ dw_w,
    const float* __restrict__ bn2_g, const float* __restrict__ bn2_b,
    const float* __restrict__ bn2_m, const float* __restrict__ bn2_v,
    const float* __restrict__ pw_w,
    const float* __restrict__ bn3_g, const float* __restrict__ bn3_b,
    const float* __restrict__ bn3_m, const float* __restrict__ bn3_v,
    const float* __restrict__ fc_w, const float* __restrict__ fc_b,
    float* __restrict__ probs_out, float* __restrict__ feat_out,
    float* __restrict__ sums, int* __restrict__ cnt)
{
    __shared__ __align__(16) float s_xr[FD * XR_STRIDE];
    __shared__ __align__(16) float s_w1[F1C * W1_STRIDE];
    __shared__ __align__(16) float s_ph[FD * PH_STRIDE];
    __shared__ float s_pwT[FD * F2C];
    __shared__ float s_feat[FEAT];
    __shared__ float s_A[FD], s_Cb[FD], s_a3[F2C], s_c3[F2C];

    const int tid = threadIdx.x;
    const int b = blockIdx.x;

    // ---- stage weights, zero xr pads, BN folds (overlaps phase-1 loads) ----
    if (tid == 0) atomicAdd(&cnt[(b & (NREP - 1)) * NCLS + y[b]], 1);
    for (int i = tid; i < F1C * KLEN; i += NTHR)
        s_w1[(i >> 6) * W1_STRIDE + (i & 63)] = conv1_w[i];
    for (int i = tid; i < F2C * FD; i += NTHR)
        s_pwT[(i & 15) * F2C + (i >> 4)] = pw_w[i];
    for (int i = tid; i < FD * 68; i += NTHR) {     // pads [0,32) & [320,356)
        int f = i / 68, p = i % 68;
        int wp = (p < 32) ? p : (288 + p);
        s_xr[f * XR_STRIDE + wp] = 0.f;
    }
    if (tid < FD) {
        const int f = tid, f1 = f >> 1;
        const float inv1 = bn1_g[f1] / sqrtf(bn1_v[f1] + 1e-3f);
        const float c1 = bn1_b[f1] - bn1_m[f1] * inv1;
        const float inv2 = bn2_g[f] / sqrtf(bn2_v[f] + 1e-3f);
        const float c2 = bn2_b[f] - bn2_m[f] * inv2;
        float sdw = 0.f;
        for (int ch = 0; ch < CH; ++ch) sdw += dw_w[f * CH + ch];
        s_A[f] = inv2 * inv1;
        s_Cb[f] = inv2 * c1 * sdw + c2;
        const float inv3 = bn3_g[f] / sqrtf(bn3_v[f] + 1e-3f);
        s_a3[f] = inv3;
        s_c3[f] = bn3_b[f] - bn3_m[f] * inv3;
    }

    // ---- phase 1: xr[f][w] = sum_ch dw[f][ch]*x[b][ch][w] (f32 -> LDS) ----
    if (tid < SW) {
        const float* xp = x + (size_t)b * (CH * SW) + tid;
        float acc[FD];
        #pragma unroll
        for (int f = 0; f < FD; ++f) acc[f] = 0.f;

#define LOADB(buf, c0)  { _Pragma("unroll") \
        for (int j = 0; j < 15; ++j) buf[j] = xp[(c0 + j) * SW]; }
#define FMAB(buf, c0)   { _Pragma("unroll") \
        for (int j = 0; j < 15; ++j) { const float xv = buf[j]; \
            _Pragma("unroll") \
            for (int f = 0; f < FD; ++f) \
                acc[f] = fmaf(dw_w[f * CH + (c0) + j], xv, acc[f]); } }

        float va[15], vb[15];
        LOADB(va, 0)
        LOADB(vb, 15)
        __builtin_amdgcn_sched_barrier(0);   // 30 loads issued before any FMA
        FMAB(va, 0)
        LOADB(va, 30)
        __builtin_amdgcn_sched_barrier(0);
        FMAB(vb, 15)
        LOADB(vb, 45)
        __builtin_amdgcn_sched_barrier(0);
        FMAB(va, 30)
        FMAB(vb, 45)
#undef LOADB
#undef FMAB
        #pragma unroll
        for (int f = 0; f < FD; ++f) s_xr[f * XR_STRIDE + 32 + tid] = acc[f];
    }
    __syncthreads();

    // ---- phase 2: K=64 conv + bn2 + elu + pool4 (16 conv outputs/thread) ----
    if (tid < 288) {
        const int f = tid & 15;
        const int q = tid >> 4;                   // 0..17
        const float4* xp = (const float4*)&s_xr[f * XR_STRIDE + 16 * q];
        const float4* wp = (const float4*)&s_w1[(f >> 1) * W1_STRIDE];
        float cw[20];
        #pragma unroll
        for (int i = 0; i < 4; ++i) {
            const float4 t = xp[i];
            cw[4*i] = t.x; cw[4*i+1] = t.y; cw[4*i+2] = t.z; cw[4*i+3] = t.w;
        }
        float bb[16];
        #pragma unroll
        for (int j = 0; j < 16; ++j) bb[j] = 0.f;
        #pragma unroll
        for (int m = 0; m < 16; ++m) {
            {
                const float4 t = xp[m + 4];
                const int s = (4 * (m + 4)) % 20;   // mult of 4, no mid-vec wrap
                cw[s] = t.x; cw[s+1] = t.y; cw[s+2] = t.z; cw[s+3] = t.w;
            }
            const float4 wv = wp[m];
            #pragma unroll
            for (int j = 0; j < 16; ++j) {
                bb[j] = fmaf(wv.x, cw[(4*m + j    ) % 20], bb[j]);
                bb[j] = fmaf(wv.y, cw[(4*m + j + 1) % 20], bb[j]);
                bb[j] = fmaf(wv.z, cw[(4*m + j + 2) % 20], bb[j]);
                bb[j] = fmaf(wv.w, cw[(4*m + j + 3) % 20], bb[j]);
            }
        }
        const float Af = s_A[f], Cf = s_Cb[f];
        float e[16];
        #pragma unroll
        for (int j = 0; j < 16; ++j) e[j] = elu1(fmaf(Af, bb[j], Cf));
        float4 ph;
        ph.x = (e[0]  + e[1]  + e[2]  + e[3])  * 0.25f;
        ph.y = (e[4]  + e[5]  + e[6]  + e[7])  * 0.25f;
        ph.z = (e[8]  + e[9]  + e[10] + e[11]) * 0.25f;
        ph.w = (e[12] + e[13] + e[14] + e[15]) * 0.25f;
        *(float4*)&s_ph[f * PH_STRIDE + 4 * q] = ph;
    }
    __syncthreads();

    // ---- phase 3: pointwise 16x16 + bn3 + elu + pool8 -> feat[144] ----
    if (tid < FEAT) {
        const int f2 = tid / NV;
        const int v = tid - f2 * NV;
        float su[8];
        #pragma unroll
        for (int k = 0; k < 8; ++k) su[k] = 0.f;
        #pragma unroll
        for (int f = 0; f < FD; ++f) {
            const float w = s_pwT[f * F2C + f2];
            const float4 p0 = *(const float4*)&s_ph[f * PH_STRIDE + 8 * v];
            const float4 p1 = *(const float4*)&s_ph[f * PH_STRIDE + 8 * v + 4];
            su[0] = fmaf(w, p0.x, su[0]); su[1] = fmaf(w, p0.y, su[1]);
            su[2] = fmaf(w, p0.z, su[2]); su[3] = fmaf(w, p0.w, su[3]);
            su[4] = fmaf(w, p1.x, su[4]); su[5] = fmaf(w, p1.y, su[5]);
            su[6] = fmaf(w, p1.z, su[6]); su[7] = fmaf(w, p1.w, su[7]);
        }
        const float a3f = s_a3[f2], c3f = s_c3[f2];
        float acc = 0.f;
        #pragma unroll
        for (int k = 0; k < 8; ++k) acc += elu1(fmaf(a3f, su[k], c3f));
        const float ft = acc * 0.125f;
        s_feat[tid] = ft;
        feat_out[(size_t)b * FEAT + tid] = ft;
        atomicAdd(&sums[((b & (NREP - 1)) * NCLS + y[b]) * FEAT + tid], ft);
    }
    __syncthreads();

    // ---- phase 4: logits + softmax (wave 0; fc_w from L2) ----
    if (tid < 64) {
        float lg0 = 0.f, lg1 = 0.f, lg2 = 0.f, lg3 = 0.f;
        for (int j = tid; j < FEAT; j += 64) {
            const float fv = s_feat[j];
            lg0 = fmaf(fv, fc_w[0 * FEAT + j], lg0);
            lg1 = fmaf(fv, fc_w[1 * FEAT + j], lg1);
            lg2 = fmaf(fv, fc_w[2 * FEAT + j], lg2);
            lg3 = fmaf(fv, fc_w[3 * FEAT + j], lg3);
        }
        #pragma unroll
        for (int off = 32; off > 0; off >>= 1) {
            lg0 += __shfl_down(lg0, off, 64);
            lg1 += __shfl_down(lg1, off, 64);
            lg2 += __shfl_down(lg2, off, 64);
            lg3 += __shfl_down(lg3, off, 64);
        }
        if (tid == 0) {
            lg0 += fc_b[0]; lg1 += fc_b[1]; lg2 += fc_b[2]; lg3 += fc_b[3];
            const float m = fmaxf(fmaxf(lg0, lg1), fmaxf(lg2, lg3));
            const float e0 = __expf(lg0 - m), e1 = __expf(lg1 - m);
            const float e2 = __expf(lg2 - m), e3 = __expf(lg3 - m);
            const float inv = 1.f / (e0 + e1 + e2 + e3);
            float* po = probs_out + (size_t)b * NCLS;
            po[0] = e0 * inv; po[1] = e1 * inv; po[2] = e2 * inv; po[3] = e3 * inv;
        }
    }
}

// ===== centroid distances (reads replicated sums + cnt) =====================
__global__ __launch_bounds__(64) void eegnet_dist(
    const float* __restrict__ feat, const int* __restrict__ y,
    const float* __restrict__ sums, const int* __restrict__ cnt,
    float* __restrict__ cl_out)
{
    __shared__ float s_cent[NCLS * FEAT];
    const int tid = threadIdx.x;
    for (int i = tid; i < NCLS * FEAT; i += 64) {
        const int c = i / FEAT;
        const int j = i - c * FEAT;
        const float sm = sums[(0 * NCLS + c) * FEAT + j]
                       + sums[(1 * NCLS + c) * FEAT + j]
                       + sums[(2 * NCLS + c) * FEAT + j]
                       + sums[(3 * NCLS + c) * FEAT + j];
        const float cf = (float)(cnt[0 * NCLS + c] + cnt[1 * NCLS + c]
                               + cnt[2 * NCLS + c] + cnt[3 * NCLS + c]);
        s_cent[i] = sm / fmaxf(cf, 1.0f);
    }
    __syncthreads();

    const int s = blockIdx.x * 64 + tid;
    const float* fp = feat + (size_t)s * FEAT;
    const float* cp = &s_cent[y[s] * FEAT];
    float acc = 0.f;
    #pragma unroll
    for (int j = 0; j < FEAT; j += 4) {
        const float4 fv = *reinterpret_cast<const float4*>(fp + j);
        float d;
        d = fv.x - cp[j + 0] + 1e-6f; acc = fmaf(d, d, acc);
        d = fv.y - cp[j + 1] + 1e-6f; acc = fmaf(d, d, acc);
        d = fv.z - cp[j + 2] + 1e-6f; acc = fmaf(d, d, acc);
        d = fv.w - cp[j + 3] + 1e-6f; acc = fmaf(d, d, acc);
    }
    float dist = sqrtf(acc);
    #pragma unroll
    for (int off = 32; off > 0; off >>= 1) dist += __shfl_down(dist, off, 64);
    if (tid == 0) atomicAdd(cl_out, dist * (1.0f / 1024.0f));
}

extern "C" void kernel_launch(void* const* d_in, const int* in_sizes, int n_in,
                              void* d_out, int out_size, void* d_ws, size_t ws_size,
                              hipStream_t stream) {
    const float* x       = (const float*)d_in[0];
    const int*   y       = (const int*)d_in[1];
    const float* conv1_w = (const float*)d_in[2];
    const float* bn1_g   = (const float*)d_in[3];
    const float* bn1_b   = (const float*)d_in[4];
    const float* bn1_m   = (const float*)d_in[5];
    const float* bn1_v   = (const float*)d_in[6];
    const float* dw_w    = (const float*)d_in[7];
    const float* bn2_g   = (const float*)d_in[8];
    const float* bn2_b   = (const float*)d_in[9];
    const float* bn2_m   = (const float*)d_in[10];
    const float* bn2_v   = (const float*)d_in[11];
    const float* pw_w    = (const float*)d_in[12];
    const float* bn3_g   = (const float*)d_in[13];
    const float* bn3_b   = (const float*)d_in[14];
    const float* bn3_m   = (const float*)d_in[15];
    const float* bn3_v   = (const float*)d_in[16];
    const float* fc_w    = (const float*)d_in[17];
    const float* fc_b    = (const float*)d_in[18];

    float* out   = (float*)d_out;
    float* probs = out;                               // [1024*4]
    float* cl    = out + 4096;                        // [1]
    char*  ws    = (char*)d_ws;
    float* sums  = (float*)ws;                        // [4][4][144] = 9216 B
    int*   cnt   = (int*)(ws + 9216);                 // [4][4] = 64 B
    float* feat  = (float*)(ws + 9280);               // 1024*144 f32, 16B-aligned

    hipMemsetAsync(ws, 0, 9280, stream);              // sums + cnt
    hipMemsetAsync(cl, 0, sizeof(float), stream);     // loss accumulator
    eegnet_fwd<<<NB, NTHR, 0, stream>>>(
        x, y, conv1_w, bn1_g, bn1_b, bn1_m, bn1_v,
        dw_w, bn2_g, bn2_b, bn2_m, bn2_v,
        pw_w, bn3_g, bn3_b, bn3_m, bn3_v,
        fc_w, fc_b, probs, feat, sums, cnt);
    eegnet_dist<<<16, 64, 0, stream>>>(feat, y, sums, cnt, cl);
}

// Round 11
// 81.529 us; speedup vs baseline: 1.4810x; 1.4810x over previous
//
#include <hip/hip_runtime.h>
#include <math.h>

#define NB   1024
#define CH   60
#define SW   288
#define F1C  8
#define FD   16   // F1*D
#define F2C  16
#define KLEN 64
#define NCLS 4
#define NV   9
#define FEAT 144
#define NTHR 320
#define NREP 4    // class-sum replicas (atomic contention / 4)
#define XCH  6    // channels per staged x-chunk

#define XR_STRIDE 356   // mult of 4 (b128-aligned rows)
#define PH_STRIDE 76
#define W1_STRIDE 68

__device__ __forceinline__ float elu1(float v) {
    return v > 0.f ? v : __expf(v) - 1.f;   // native v_exp_f32
}

// ===== fused per-sample forward: chreduce -> conv -> pointwise -> softmax ===
// 1024 blocks x 320 threads, 4 blocks/CU co-resident (LDS 38.6KB, VGPR<=64).
// Phase 1 = cooperative chunked staging: x arrives via coalesced float4 LDS
// tiles (<=2 loads/thread -> no per-thread MLP needed); FMAs read LDS.
__global__ __launch_bounds__(NTHR, 8) void eegnet_fwd(
    const float* __restrict__ x, const int* __restrict__ y,
    const float* __restrict__ conv1_w,
    const float* __restrict__ bn1_g, const float* __restrict__ bn1_b,
    const float* __restrict__ bn1_m, const float* __restrict__ bn1_v,
    const float* __restrict__ dw_w,
    const float* __restrict__ bn2_g, const float* __restrict__ bn2_b,
    const float* __restrict__ bn2_m, const float* __restrict__ bn2_v,
    const float* __restrict__ pw_w,
    const float* __restrict__ bn3_g, const float* __restrict__ bn3_b,
    const float* __restrict__ bn3_m, const float* __restrict__ bn3_v,
    const float* __restrict__ fc_w, const float* __restrict__ fc_b,
    float* __restrict__ probs_out, float* __restrict__ feat_out,
    float* __restrict__ sums, int* __restrict__ cnt)
{
    __shared__ __align__(16) float s_x[XCH * SW];      // 6.9 KB staging tile
    __shared__ __align__(16) float s_xr[FD * XR_STRIDE];
    __shared__ __align__(16) float s_w1[F1C * W1_STRIDE];
    __shared__ __align__(16) float s_ph[FD * PH_STRIDE];
    __shared__ float s_pwT[FD * F2C];
    __shared__ float s_feat[FEAT];
    __shared__ float s_A[FD], s_Cb[FD], s_a3[F2C], s_c3[F2C];

    const int tid = threadIdx.x;
    const int b = blockIdx.x;

    // ---- stage weights, zero xr pads, BN folds (no barrier needed yet) ----
    if (tid == 0) atomicAdd(&cnt[(b & (NREP - 1)) * NCLS + y[b]], 1);
    for (int i = tid; i < F1C * KLEN; i += NTHR)
        s_w1[(i >> 6) * W1_STRIDE + (i & 63)] = conv1_w[i];
    for (int i = tid; i < F2C * FD; i += NTHR)
        s_pwT[(i & 15) * F2C + (i >> 4)] = pw_w[i];
    for (int i = tid; i < FD * 68; i += NTHR) {     // pads [0,32) & [320,356)
        int f = i / 68, p = i % 68;
        int wp = (p < 32) ? p : (288 + p);
        s_xr[f * XR_STRIDE + wp] = 0.f;
    }
    if (tid < FD) {
        const int f = tid, f1 = f >> 1;
        const float inv1 = bn1_g[f1] / sqrtf(bn1_v[f1] + 1e-3f);
        const float c1 = bn1_b[f1] - bn1_m[f1] * inv1;
        const float inv2 = bn2_g[f] / sqrtf(bn2_v[f] + 1e-3f);
        const float c2 = bn2_b[f] - bn2_m[f] * inv2;
        float sdw = 0.f;
        for (int ch = 0; ch < CH; ++ch) sdw += dw_w[f * CH + ch];
        s_A[f] = inv2 * inv1;
        s_Cb[f] = inv2 * c1 * sdw + c2;
        const float inv3 = bn3_g[f] / sqrtf(bn3_v[f] + 1e-3f);
        s_a3[f] = inv3;
        s_c3[f] = bn3_b[f] - bn3_m[f] * inv3;
    }

    // ---- phase 1: xr[f][w] = sum_ch dw[f][ch]*x[b][ch][w] via LDS chunks ----
    {
        const float4* xb4 = (const float4*)(x + (size_t)b * (CH * SW));
        float4* sx4 = (float4*)s_x;
        float acc[FD];
        #pragma unroll
        for (int f = 0; f < FD; ++f) acc[f] = 0.f;
        #pragma unroll
        for (int c0 = 0; c0 < CH; c0 += XCH) {
            // stage 6x288 floats = 432 float4, coalesced
            const float4* src = xb4 + c0 * 72;     // 72 float4 per channel row
            sx4[tid] = src[tid];                   // tid < 432 always
            if (tid < 432 - NTHR) sx4[tid + NTHR] = src[tid + NTHR];
            __syncthreads();
            if (tid < SW) {
                #pragma unroll
                for (int r = 0; r < XCH; ++r) {
                    const float xv = s_x[r * SW + tid];   // 2-way bank = free
                    #pragma unroll
                    for (int f = 0; f < FD; ++f)
                        acc[f] = fmaf(dw_w[f * CH + c0 + r], xv, acc[f]); // s_load
                }
            }
            __syncthreads();                       // protect next chunk's stores
        }
        if (tid < SW) {
            #pragma unroll
            for (int f = 0; f < FD; ++f) s_xr[f * XR_STRIDE + 32 + tid] = acc[f];
        }
    }
    __syncthreads();

    // ---- phase 2: K=64 conv + bn2 + elu + pool4 (16 conv outputs/thread) ----
    if (tid < 288) {
        const int f = tid & 15;
        const int q = tid >> 4;                   // 0..17
        const float4* xp = (const float4*)&s_xr[f * XR_STRIDE + 16 * q];
        const float4* wp = (const float4*)&s_w1[(f >> 1) * W1_STRIDE];
        float cw[20];
        #pragma unroll
        for (int i = 0; i < 4; ++i) {
            const float4 t = xp[i];
            cw[4*i] = t.x; cw[4*i+1] = t.y; cw[4*i+2] = t.z; cw[4*i+3] = t.w;
        }
        float bb[16];
        #pragma unroll
        for (int j = 0; j < 16; ++j) bb[j] = 0.f;
        #pragma unroll
        for (int m = 0; m < 16; ++m) {
            {
                const float4 t = xp[m + 4];
                const int s = (4 * (m + 4)) % 20;   // mult of 4, no mid-vec wrap
                cw[s] = t.x; cw[s+1] = t.y; cw[s+2] = t.z; cw[s+3] = t.w;
            }
            const float4 wv = wp[m];
            #pragma unroll
            for (int j = 0; j < 16; ++j) {
                bb[j] = fmaf(wv.x, cw[(4*m + j    ) % 20], bb[j]);
                bb[j] = fmaf(wv.y, cw[(4*m + j + 1) % 20], bb[j]);
                bb[j] = fmaf(wv.z, cw[(4*m + j + 2) % 20], bb[j]);
                bb[j] = fmaf(wv.w, cw[(4*m + j + 3) % 20], bb[j]);
            }
        }
        const float Af = s_A[f], Cf = s_Cb[f];
        float e[16];
        #pragma unroll
        for (int j = 0; j < 16; ++j) e[j] = elu1(fmaf(Af, bb[j], Cf));
        float4 ph;
        ph.x = (e[0]  + e[1]  + e[2]  + e[3])  * 0.25f;
        ph.y = (e[4]  + e[5]  + e[6]  + e[7])  * 0.25f;
        ph.z = (e[8]  + e[9]  + e[10] + e[11]) * 0.25f;
        ph.w = (e[12] + e[13] + e[14] + e[15]) * 0.25f;
        *(float4*)&s_ph[f * PH_STRIDE + 4 * q] = ph;
    }
    __syncthreads();

    // ---- phase 3: pointwise 16x16 + bn3 + elu + pool8 -> feat[144] ----
    if (tid < FEAT) {
        const int f2 = tid / NV;
        const int v = tid - f2 * NV;
        float su[8];
        #pragma unroll
        for (int k = 0; k < 8; ++k) su[k] = 0.f;
        #pragma unroll
        for (int f = 0; f < FD; ++f) {
            const float w = s_pwT[f * F2C + f2];
            const float4 p0 = *(const float4*)&s_ph[f * PH_STRIDE + 8 * v];
            const float4 p1 = *(const float4*)&s_ph[f * PH_STRIDE + 8 * v + 4];
            su[0] = fmaf(w, p0.x, su[0]); su[1] = fmaf(w, p0.y, su[1]);
            su[2] = fmaf(w, p0.z, su[2]); su[3] = fmaf(w, p0.w, su[3]);
            su[4] = fmaf(w, p1.x, su[4]); su[5] = fmaf(w, p1.y, su[5]);
            su[6] = fmaf(w, p1.z, su[6]); su[7] = fmaf(w, p1.w, su[7]);
        }
        const float a3f = s_a3[f2], c3f = s_c3[f2];
        float acc = 0.f;
        #pragma unroll
        for (int k = 0; k < 8; ++k) acc += elu1(fmaf(a3f, su[k], c3f));
        const float ft = acc * 0.125f;
        s_feat[tid] = ft;
        feat_out[(size_t)b * FEAT + tid] = ft;
        atomicAdd(&sums[((b & (NREP - 1)) * NCLS + y[b]) * FEAT + tid], ft);
    }
    __syncthreads();

    // ---- phase 4: logits + softmax (wave 0; fc_w from L2) ----
    if (tid < 64) {
        float lg0 = 0.f, lg1 = 0.f, lg2 = 0.f, lg3 = 0.f;
        for (int j = tid; j < FEAT; j += 64) {
            const float fv = s_feat[j];
            lg0 = fmaf(fv, fc_w[0 * FEAT + j], lg0);
            lg1 = fmaf(fv, fc_w[1 * FEAT + j], lg1);
            lg2 = fmaf(fv, fc_w[2 * FEAT + j], lg2);
            lg3 = fmaf(fv, fc_w[3 * FEAT + j], lg3);
        }
        #pragma unroll
        for (int off = 32; off > 0; off >>= 1) {
            lg0 += __shfl_down(lg0, off, 64);
            lg1 += __shfl_down(lg1, off, 64);
            lg2 += __shfl_down(lg2, off, 64);
            lg3 += __shfl_down(lg3, off, 64);
        }
        if (tid == 0) {
            lg0 += fc_b[0]; lg1 += fc_b[1]; lg2 += fc_b[2]; lg3 += fc_b[3];
            const float m = fmaxf(fmaxf(lg0, lg1), fmaxf(lg2, lg3));
            const float e0 = __expf(lg0 - m), e1 = __expf(lg1 - m);
            const float e2 = __expf(lg2 - m), e3 = __expf(lg3 - m);
            const float inv = 1.f / (e0 + e1 + e2 + e3);
            float* po = probs_out + (size_t)b * NCLS;
            po[0] = e0 * inv; po[1] = e1 * inv; po[2] = e2 * inv; po[3] = e3 * inv;
        }
    }
}

// ===== centroid distances (reads replicated sums + cnt) =====================
__global__ __launch_bounds__(64) void eegnet_dist(
    const float* __restrict__ feat, const int* __restrict__ y,
    const float* __restrict__ sums, const int* __restrict__ cnt,
    float* __restrict__ cl_out)
{
    __shared__ float s_cent[NCLS * FEAT];
    const int tid = threadIdx.x;
    for (int i = tid; i < NCLS * FEAT; i += 64) {
        const int c = i / FEAT;
        const int j = i - c * FEAT;
        const float sm = sums[(0 * NCLS + c) * FEAT + j]
                       + sums[(1 * NCLS + c) * FEAT + j]
                       + sums[(2 * NCLS + c) * FEAT + j]
                       + sums[(3 * NCLS + c) * FEAT + j];
        const float cf = (float)(cnt[0 * NCLS + c] + cnt[1 * NCLS + c]
                               + cnt[2 * NCLS + c] + cnt[3 * NCLS + c]);
        s_cent[i] = sm / fmaxf(cf, 1.0f);
    }
    __syncthreads();

    const int s = blockIdx.x * 64 + tid;
    const float* fp = feat + (size_t)s * FEAT;
    const float* cp = &s_cent[y[s] * FEAT];
    float acc = 0.f;
    #pragma unroll
    for (int j = 0; j < FEAT; j += 4) {
        const float4 fv = *reinterpret_cast<const float4*>(fp + j);
        float d;
        d = fv.x - cp[j + 0] + 1e-6f; acc = fmaf(d, d, acc);
        d = fv.y - cp[j + 1] + 1e-6f; acc = fmaf(d, d, acc);
        d = fv.z - cp[j + 2] + 1e-6f; acc = fmaf(d, d, acc);
        d = fv.w - cp[j + 3] + 1e-6f; acc = fmaf(d, d, acc);
    }
    float dist = sqrtf(acc);
    #pragma unroll
    for (int off = 32; off > 0; off >>= 1) dist += __shfl_down(dist, off, 64);
    if (tid == 0) atomicAdd(cl_out, dist * (1.0f / 1024.0f));
}

extern "C" void kernel_launch(void* const* d_in, const int* in_sizes, int n_in,
                              void* d_out, int out_size, void* d_ws, size_t ws_size,
                              hipStream_t stream) {
    const float* x       = (const float*)d_in[0];
    const int*   y       = (const int*)d_in[1];
    const float* conv1_w = (const float*)d_in[2];
    const float* bn1_g   = (const float*)d_in[3];
    const float* bn1_b   = (const float*)d_in[4];
    const float* bn1_m   = (const float*)d_in[5];
    const float* bn1_v   = (const float*)d_in[6];
    const float* dw_w    = (const float*)d_in[7];
    const float* bn2_g   = (const float*)d_in[8];
    const float* bn2_b   = (const float*)d_in[9];
    const float* bn2_m   = (const float*)d_in[10];
    const float* bn2_v   = (const float*)d_in[11];
    const float* pw_w    = (const float*)d_in[12];
    const float* bn3_g   = (const float*)d_in[13];
    const float* bn3_b   = (const float*)d_in[14];
    const float* bn3_m   = (const float*)d_in[15];
    const float* bn3_v   = (const float*)d_in[16];
    const float* fc_w    = (const float*)d_in[17];
    const float* fc_b    = (const float*)d_in[18];

    float* out   = (float*)d_out;
    float* probs = out;                               // [1024*4]
    float* cl    = out + 4096;                        // [1]
    char*  ws    = (char*)d_ws;
    float* sums  = (float*)ws;                        // [4][4][144] = 9216 B
    int*   cnt   = (int*)(ws + 9216);                 // [4][4] = 64 B
    float* feat  = (float*)(ws + 9280);               // 1024*144 f32, 16B-aligned

    hipMemsetAsync(ws, 0, 9280, stream);              // sums + cnt
    hipMemsetAsync(cl, 0, sizeof(float), stream);     // loss accumulator
    eegnet_fwd<<<NB, NTHR, 0, stream>>>(
        x, y, conv1_w, bn1_g, bn1_b, bn1_m, bn1_v,
        dw_w, bn2_g, bn2_b, bn2_m, bn2_v,
        pw_w, bn3_g, bn3_b, bn3_m, bn3_v,
        fc_w, fc_b, probs, feat, sums, cnt);
    eegnet_dist<<<16, 64, 0, stream>>>(feat, y, sums, cnt, cl);
}

// Round 12
// 67.958 us; speedup vs baseline: 1.7768x; 1.1997x over previous
//
#include <hip/hip_runtime.h>
#include <math.h>

#define NB   1024
#define CH   60
#define SW   288
#define F1C  8
#define FD   16   // F1*D
#define F2C  16
#define KLEN 64
#define NCLS 4
#define NV   9
#define FEAT 144
#define NTHR 320
#define NREP 4    // class-sum replicas (atomic contention / 4)
#define XCH  6    // channels per staged chunk (10 chunks)
#define CHK  (XCH * SW)        // 1728 floats per chunk
#define CHK4 (CHK / 4)         // 432 float4 per chunk

#define XR_STRIDE 356   // mult of 4 (b128-aligned rows)
#define PH_STRIDE 76
#define W1_STRIDE 68

__device__ __forceinline__ float elu1(float v) {
    return v > 0.f ? v : __expf(v) - 1.f;   // native v_exp_f32
}

// ===== fused per-sample forward =============================================
// 1024 blocks x 320 threads, exactly 4 blocks/CU (LDS 40.1 KB, VGPR<=64).
// Phase 1 = double-buffered reg-staged LDS pipeline (T14 issue-early /
// write-late): chunk k+1's global loads are issued right after chunk k's
// ds_write and stay in flight across the barrier + FMA block. Per-wave
// serial chain ~10x300cy instead of 60x600cy.
__global__ __launch_bounds__(NTHR, 8) void eegnet_fwd(
    const float* __restrict__ x, const int* __restrict__ y,
    const float* __restrict__ conv1_w,
    const float* __restrict__ bn1_g, const float* __restrict__ bn1_b,
    const float* __restrict__ bn1_m, const float* __restrict__ bn1_v,
    const float* __restrict__ dw_w,
    const float* __restrict__ bn2_g, const float* __restrict__ bn2_b,
    const float* __restrict__ bn2_m, const float* __restrict__ bn2_v,
    const float* __restrict__ pw_w,
    const float* __restrict__ bn3_g, const float* __restrict__ bn3_b,
    const float* __restrict__ bn3_m, const float* __restrict__ bn3_v,
    const float* __restrict__ fc_w, const float* __restrict__ fc_b,
    float* __restrict__ probs_out, float* __restrict__ feat_out,
    float* __restrict__ sums, int* __restrict__ cnt, float* __restrict__ cl)
{
    __shared__ __align__(16) float s_xr[FD * XR_STRIDE];   // 22784 B
    __shared__ __align__(16) float s_un[2 * CHK];          // 13824 B (x-chunks; later s_ph+s_feat)
    __shared__ __align__(16) float s_w1[F1C * W1_STRIDE];  // 2176 B
    __shared__ float s_pwT[FD * F2C];                      // 1024 B
    __shared__ float s_A[FD], s_Cb[FD], s_a3[F2C], s_c3[F2C];

    float* const s_ph   = s_un;          // 1216 floats, reused after phase 1
    float* const s_feat = s_un + 1280;   // 144 floats (16B-aligned offset)

    const int tid = threadIdx.x;
    const int b = blockIdx.x;

    // ---- stage weights, zero xr pads, BN folds ----
    if (tid == 0) {
        atomicAdd(&cnt[(b & (NREP - 1)) * NCLS + y[b]], 1);
        if (b == 0) cl[0] = 0.f;         // dist kernel runs after fwd completes
    }
    for (int i = tid; i < F1C * KLEN; i += NTHR)
        s_w1[(i >> 6) * W1_STRIDE + (i & 63)] = conv1_w[i];
    for (int i = tid; i < F2C * FD; i += NTHR)
        s_pwT[(i & 15) * F2C + (i >> 4)] = pw_w[i];
    for (int i = tid; i < FD * 68; i += NTHR) {     // pads [0,32) & [320,356)
        int f = i / 68, p = i % 68;
        int wp = (p < 32) ? p : (288 + p);
        s_xr[f * XR_STRIDE + wp] = 0.f;
    }
    if (tid < FD) {
        const int f = tid, f1 = f >> 1;
        const float inv1 = bn1_g[f1] / sqrtf(bn1_v[f1] + 1e-3f);
        const float c1 = bn1_b[f1] - bn1_m[f1] * inv1;
        const float inv2 = bn2_g[f] / sqrtf(bn2_v[f] + 1e-3f);
        const float c2 = bn2_b[f] - bn2_m[f] * inv2;
        float sdw = 0.f;
        for (int ch = 0; ch < CH; ++ch) sdw += dw_w[f * CH + ch];
        s_A[f] = inv2 * inv1;
        s_Cb[f] = inv2 * c1 * sdw + c2;
        const float inv3 = bn3_g[f] / sqrtf(bn3_v[f] + 1e-3f);
        s_a3[f] = inv3;
        s_c3[f] = bn3_b[f] - bn3_m[f] * inv3;
    }

    // ---- phase 1: xr[f][w] = sum_ch dw[f][ch]*x[b][ch][w], pipelined ----
    {
        const float4* xb4 = (const float4*)(x + (size_t)b * (CH * SW));
        const bool hasb = (tid < CHK4 - NTHR);     // 112 threads carry 2nd slot
        float4 ra, rb;
        ra = xb4[tid];                              // prologue: chunk 0
        if (hasb) rb = xb4[tid + NTHR];
        float acc[FD];
        #pragma unroll
        for (int f = 0; f < FD; ++f) acc[f] = 0.f;

        #pragma unroll
        for (int k = 0; k < CH / XCH; ++k) {        // 10 chunks, fully unrolled
            float* sb = s_un + (k & 1) * CHK;
            ((float4*)sb)[tid] = ra;                // write chunk k (vmcnt wait here)
            if (hasb) ((float4*)sb)[tid + NTHR] = rb;
            if (k < CH / XCH - 1) {                 // issue chunk k+1 NOW
                const float4* src = xb4 + (k + 1) * CHK4;
                ra = src[tid];
                if (hasb) rb = src[tid + NTHR];
            }
            __syncthreads();                        // chunk k visible to all
            if (tid < SW) {
                #pragma unroll
                for (int r = 0; r < XCH; ++r) {
                    const float xv = sb[r * SW + tid];    // stride-1, conflict-free
                    #pragma unroll
                    for (int f = 0; f < FD; ++f)
                        acc[f] = fmaf(dw_w[f * CH + XCH * k + r], xv, acc[f]); // s_load
                }
            }
            // single barrier/iter: buffer reuse is 2 iters apart, so the
            // next iteration's barrier orders FMA-reads vs overwrites.
        }
        if (tid < SW) {
            #pragma unroll
            for (int f = 0; f < FD; ++f) s_xr[f * XR_STRIDE + 32 + tid] = acc[f];
        }
    }
    __syncthreads();    // phase-1 reads of s_un done; s_ph may now overwrite it

    // ---- phase 2: K=64 conv + bn2 + elu + pool4 (16 conv outputs/thread) ----
    if (tid < 288) {
        const int f = tid & 15;
        const int q = tid >> 4;                   // 0..17
        const float4* xp = (const float4*)&s_xr[f * XR_STRIDE + 16 * q];
        const float4* wp = (const float4*)&s_w1[(f >> 1) * W1_STRIDE];
        float cw[20];
        #pragma unroll
        for (int i = 0; i < 4; ++i) {
            const float4 t = xp[i];
            cw[4*i] = t.x; cw[4*i+1] = t.y; cw[4*i+2] = t.z; cw[4*i+3] = t.w;
        }
        float bb[16];
        #pragma unroll
        for (int j = 0; j < 16; ++j) bb[j] = 0.f;
        #pragma unroll
        for (int m = 0; m < 16; ++m) {
            {
                const float4 t = xp[m + 4];
                const int s = (4 * (m + 4)) % 20;   // mult of 4, no mid-vec wrap
                cw[s] = t.x; cw[s+1] = t.y; cw[s+2] = t.z; cw[s+3] = t.w;
            }
            const float4 wv = wp[m];
            #pragma unroll
            for (int j = 0; j < 16; ++j) {
                bb[j] = fmaf(wv.x, cw[(4*m + j    ) % 20], bb[j]);
                bb[j] = fmaf(wv.y, cw[(4*m + j + 1) % 20], bb[j]);
                bb[j] = fmaf(wv.z, cw[(4*m + j + 2) % 20], bb[j]);
                bb[j] = fmaf(wv.w, cw[(4*m + j + 3) % 20], bb[j]);
            }
        }
        const float Af = s_A[f], Cf = s_Cb[f];
        float e[16];
        #pragma unroll
        for (int j = 0; j < 16; ++j) e[j] = elu1(fmaf(Af, bb[j], Cf));
        float4 ph;
        ph.x = (e[0]  + e[1]  + e[2]  + e[3])  * 0.25f;
        ph.y = (e[4]  + e[5]  + e[6]  + e[7])  * 0.25f;
        ph.z = (e[8]  + e[9]  + e[10] + e[11]) * 0.25f;
        ph.w = (e[12] + e[13] + e[14] + e[15]) * 0.25f;
        *(float4*)&s_ph[f * PH_STRIDE + 4 * q] = ph;
    }
    __syncthreads();

    // ---- phase 3: pointwise 16x16 + bn3 + elu + pool8 -> feat[144] ----
    if (tid < FEAT) {
        const int f2 = tid / NV;
        const int v = tid - f2 * NV;
        float su[8];
        #pragma unroll
        for (int k = 0; k < 8; ++k) su[k] = 0.f;
        #pragma unroll
        for (int f = 0; f < FD; ++f) {
            const float w = s_pwT[f * F2C + f2];
            const float4 p0 = *(const float4*)&s_ph[f * PH_STRIDE + 8 * v];
            const float4 p1 = *(const float4*)&s_ph[f * PH_STRIDE + 8 * v + 4];
            su[0] = fmaf(w, p0.x, su[0]); su[1] = fmaf(w, p0.y, su[1]);
            su[2] = fmaf(w, p0.z, su[2]); su[3] = fmaf(w, p0.w, su[3]);
            su[4] = fmaf(w, p1.x, su[4]); su[5] = fmaf(w, p1.y, su[5]);
            su[6] = fmaf(w, p1.z, su[6]); su[7] = fmaf(w, p1.w, su[7]);
        }
        const float a3f = s_a3[f2], c3f = s_c3[f2];
        float acc = 0.f;
        #pragma unroll
        for (int k = 0; k < 8; ++k) acc += elu1(fmaf(a3f, su[k], c3f));
        const float ft = acc * 0.125f;
        s_feat[tid] = ft;
        feat_out[(size_t)b * FEAT + tid] = ft;
        atomicAdd(&sums[((b & (NREP - 1)) * NCLS + y[b]) * FEAT + tid], ft);
    }
    __syncthreads();

    // ---- phase 4: logits + softmax (wave 0; fc_w from L2) ----
    if (tid < 64) {
        float lg0 = 0.f, lg1 = 0.f, lg2 = 0.f, lg3 = 0.f;
        for (int j = tid; j < FEAT; j += 64) {
            const float fv = s_feat[j];
            lg0 = fmaf(fv, fc_w[0 * FEAT + j], lg0);
            lg1 = fmaf(fv, fc_w[1 * FEAT + j], lg1);
            lg2 = fmaf(fv, fc_w[2 * FEAT + j], lg2);
            lg3 = fmaf(fv, fc_w[3 * FEAT + j], lg3);
        }
        #pragma unroll
        for (int off = 32; off > 0; off >>= 1) {
            lg0 += __shfl_down(lg0, off, 64);
            lg1 += __shfl_down(lg1, off, 64);
            lg2 += __shfl_down(lg2, off, 64);
            lg3 += __shfl_down(lg3, off, 64);
        }
        if (tid == 0) {
            lg0 += fc_b[0]; lg1 += fc_b[1]; lg2 += fc_b[2]; lg3 += fc_b[3];
            const float m = fmaxf(fmaxf(lg0, lg1), fmaxf(lg2, lg3));
            const float e0 = __expf(lg0 - m), e1 = __expf(lg1 - m);
            const float e2 = __expf(lg2 - m), e3 = __expf(lg3 - m);
            const float inv = 1.f / (e0 + e1 + e2 + e3);
            float* po = probs_out + (size_t)b * NCLS;
            po[0] = e0 * inv; po[1] = e1 * inv; po[2] = e2 * inv; po[3] = e3 * inv;
        }
    }
}

// ===== centroid distances (reads replicated sums + cnt) =====================
__global__ __launch_bounds__(64) void eegnet_dist(
    const float* __restrict__ feat, const int* __restrict__ y,
    const float* __restrict__ sums, const int* __restrict__ cnt,
    float* __restrict__ cl_out)
{
    __shared__ float s_cent[NCLS * FEAT];
    const int tid = threadIdx.x;
    for (int i = tid; i < NCLS * FEAT; i += 64) {
        const int c = i / FEAT;
        const int j = i - c * FEAT;
        const float sm = sums[(0 * NCLS + c) * FEAT + j]
                       + sums[(1 * NCLS + c) * FEAT + j]
                       + sums[(2 * NCLS + c) * FEAT + j]
                       + sums[(3 * NCLS + c) * FEAT + j];
        const float cf = (float)(cnt[0 * NCLS + c] + cnt[1 * NCLS + c]
                               + cnt[2 * NCLS + c] + cnt[3 * NCLS + c]);
        s_cent[i] = sm / fmaxf(cf, 1.0f);
    }
    __syncthreads();

    const int s = blockIdx.x * 64 + tid;
    const float* fp = feat + (size_t)s * FEAT;
    const float* cp = &s_cent[y[s] * FEAT];
    float acc = 0.f;
    #pragma unroll
    for (int j = 0; j < FEAT; j += 4) {
        const float4 fv = *reinterpret_cast<const float4*>(fp + j);
        float d;
        d = fv.x - cp[j + 0] + 1e-6f; acc = fmaf(d, d, acc);
        d = fv.y - cp[j + 1] + 1e-6f; acc = fmaf(d, d, acc);
        d = fv.z - cp[j + 2] + 1e-6f; acc = fmaf(d, d, acc);
        d = fv.w - cp[j + 3] + 1e-6f; acc = fmaf(d, d, acc);
    }
    float dist = sqrtf(acc);
    #pragma unroll
    for (int off = 32; off > 0; off >>= 1) dist += __shfl_down(dist, off, 64);
    if (tid == 0) atomicAdd(cl_out, dist * (1.0f / 1024.0f));
}

extern "C" void kernel_launch(void* const* d_in, const int* in_sizes, int n_in,
                              void* d_out, int out_size, void* d_ws, size_t ws_size,
                              hipStream_t stream) {
    const float* x       = (const float*)d_in[0];
    const int*   y       = (const int*)d_in[1];
    const float* conv1_w = (const float*)d_in[2];
    const float* bn1_g   = (const float*)d_in[3];
    const float* bn1_b   = (const float*)d_in[4];
    const float* bn1_m   = (const float*)d_in[5];
    const float* bn1_v   = (const float*)d_in[6];
    const float* dw_w    = (const float*)d_in[7];
    const float* bn2_g   = (const float*)d_in[8];
    const float* bn2_b   = (const float*)d_in[9];
    const float* bn2_m   = (const float*)d_in[10];
    const float* bn2_v   = (const float*)d_in[11];
    const float* pw_w    = (const float*)d_in[12];
    const float* bn3_g   = (const float*)d_in[13];
    const float* bn3_b   = (const float*)d_in[14];
    const float* bn3_m   = (const float*)d_in[15];
    const float* bn3_v   = (const float*)d_in[16];
    const float* fc_w    = (const float*)d_in[17];
    const float* fc_b    = (const float*)d_in[18];

    float* out   = (float*)d_out;
    float* probs = out;                               // [1024*4]
    float* cl    = out + 4096;                        // [1]
    char*  ws    = (char*)d_ws;
    float* sums  = (float*)ws;                        // [4][4][144] = 9216 B
    int*   cnt   = (int*)(ws + 9216);                 // [4][4] = 64 B
    float* feat  = (float*)(ws + 9280);               // 1024*144 f32, 16B-aligned

    hipMemsetAsync(ws, 0, 9280, stream);              // sums + cnt (cl zeroed in fwd)
    eegnet_fwd<<<NB, NTHR, 0, stream>>>(
        x, y, conv1_w, bn1_g, bn1_b, bn1_m, bn1_v,
        dw_w, bn2_g, bn2_b, bn2_m, bn2_v,
        pw_w, bn3_g, bn3_b, bn3_m, bn3_v,
        fc_w, fc_b, probs, feat, sums, cnt, cl);
    eegnet_dist<<<16, 64, 0, stream>>>(feat, y, sums, cnt, cl);
}